// Round 2
// baseline (116.983 us; speedup 1.0000x reference)
//
#include <hip/hip_runtime.h>
#include <math.h>

#define BDIM 4
#define DIM 512
#define TT 2048
#define CDIM 14
#define NTOK (BDIM * TT)              // 8192 tokens
#define NB 16384                      // 2^14 codes
#define OUT_ELEMS (BDIM * DIM * TT)   // 4194304
#define FEPS 1e-20f

// ws layout
#define WS_HIST_OFF 0                 // 16384 f32 = 64 KB
#define WS_PSE_OFF 65536              // 256 f32
#define WS_COM_OFF 66560              // 256 f32
#define WS_PW_OFF  67584              // 4*14*8192 f32 = 1.75 MB
#define WS_NEED (67584 + 4 * 14 * 8192 * 4)

// ---------------------------------------------------------------------------
// Fast path kernel A: partial h. Grid 512 blocks x 256 thr.
// block = (token tile of 64) x (d-group of 128). Wave w covers 32 d's:
// lanes = 16 t-lanes (float4 tokens) x 4 d-rows. Shuffle-reduce over d-rows,
// LDS-reduce over the 4 waves, write pw[dgrp][c][token] (coalesced for B).
// ---------------------------------------------------------------------------
__global__ __launch_bounds__(256) void k_partial(
    const float* __restrict__ x,
    const float* __restrict__ W_in,
    float* __restrict__ pw)
{
    __shared__ float Wl[128][16];     // 8 KB, W rows for this d-group
    __shared__ float sred[4][64][15]; // 15 KB, padded to kill bank conflicts

    const int tid = threadIdx.x;
    const int bid = blockIdx.x;
    const int tile = bid >> 2;        // 0..127 (64 tokens each)
    const int dgrp = bid & 3;         // 0..3  (128 d's each)
    const int d0 = dgrp * 128;

    for (int i = tid; i < 128 * CDIM; i += 256) {
        const int c = i >> 7;
        const int r = i & 127;
        Wl[r][c] = W_in[c * DIM + d0 + r];
    }
    __syncthreads();

    const int w = tid >> 6;
    const int lane = tid & 63;
    const int tl = lane & 15;
    const int dr = lane >> 4;

    const int tok0 = tile * 64 + tl * 4;
    const int b = tok0 >> 11;
    const int t = tok0 & (TT - 1);
    const int wd0 = w * 32;

    float acc[4][14];
#pragma unroll
    for (int j = 0; j < 4; ++j)
#pragma unroll
        for (int c = 0; c < 14; ++c) acc[j][c] = 0.f;

#pragma unroll
    for (int i = 0; i < 8; ++i) {
        const int r = wd0 + i * 4 + dr;             // row within d-group
        const float4 xv = *(const float4*)(x + ((size_t)(b * DIM + d0 + r) * TT + t));
        const float4* wr = (const float4*)(&Wl[r][0]);
        const float4 w0 = wr[0];
        const float4 w1 = wr[1];
        const float4 w2 = wr[2];
        const float2 w3 = ((const float2*)wr)[6];
        const float xs[4] = {xv.x, xv.y, xv.z, xv.w};
#pragma unroll
        for (int j = 0; j < 4; ++j) {
            const float v = xs[j];
            acc[j][0]  = fmaf(v, w0.x, acc[j][0]);
            acc[j][1]  = fmaf(v, w0.y, acc[j][1]);
            acc[j][2]  = fmaf(v, w0.z, acc[j][2]);
            acc[j][3]  = fmaf(v, w0.w, acc[j][3]);
            acc[j][4]  = fmaf(v, w1.x, acc[j][4]);
            acc[j][5]  = fmaf(v, w1.y, acc[j][5]);
            acc[j][6]  = fmaf(v, w1.z, acc[j][6]);
            acc[j][7]  = fmaf(v, w1.w, acc[j][7]);
            acc[j][8]  = fmaf(v, w2.x, acc[j][8]);
            acc[j][9]  = fmaf(v, w2.y, acc[j][9]);
            acc[j][10] = fmaf(v, w2.z, acc[j][10]);
            acc[j][11] = fmaf(v, w2.w, acc[j][11]);
            acc[j][12] = fmaf(v, w3.x, acc[j][12]);
            acc[j][13] = fmaf(v, w3.y, acc[j][13]);
        }
    }

    // reduce over the 4 d-rows (lane bits 4 and 5)
#pragma unroll
    for (int j = 0; j < 4; ++j)
#pragma unroll
        for (int c = 0; c < 14; ++c) {
            float v = acc[j][c];
            v += __shfl_xor(v, 16);
            v += __shfl_xor(v, 32);
            acc[j][c] = v;
        }

    if (dr == 0) {
#pragma unroll
        for (int j = 0; j < 4; ++j)
#pragma unroll
            for (int c = 0; c < 14; ++c)
                sred[w][tl * 4 + j][c] = acc[j][c];
    }
    __syncthreads();

    // combine the 4 waves' chunks -> block partial over 128 d's
    for (int p = tid; p < 64 * CDIM; p += 256) {
        const int c = p >> 6;          // p = c*64 + tok_local
        const int tk = p & 63;
        const float s = sred[0][tk][c] + sred[1][tk][c] + sred[2][tk][c] + sred[3][tk][c];
        pw[((dgrp * CDIM + c) << 13) + tile * 64 + tk] = s;
    }
}

// ---------------------------------------------------------------------------
// Fast path kernel B: per-token tail. 1 thread per token.
// ---------------------------------------------------------------------------
__global__ __launch_bounds__(256) void k_tail(
    const float* __restrict__ pw,
    const float* __restrict__ b_in,
    float* __restrict__ out_idx,
    float* __restrict__ hist,
    float* __restrict__ pse_part,
    float* __restrict__ commit_part)
{
    __shared__ float sc[256];
    const int tid = threadIdx.x;
    const int tok = blockIdx.x * 256 + tid;

    float h[14];
#pragma unroll
    for (int c = 0; c < 14; ++c) {
        float s = b_in[c];
#pragma unroll
        for (int g = 0; g < 4; ++g)
            s += pw[((g * CDIM + c) << 13) + tok];
        h[c] = s;
    }

    unsigned int idx = 0;
    float p[14];
    float pse = 0.f, commit = 0.f;
#pragma unroll
    for (int c = 0; c < 14; ++c) {
        const float hc = h[c];
        const bool pos = hc > 0.f;
        if (pos) idx |= (1u << (13 - c));
        const float sgn = pos ? 1.f : -1.f;
        const float dlt = hc - sgn;
        commit += dlt * dlt;
        const float pc = 1.f / (1.f + expf(-400.f * hc));
        p[c] = pc;
        const float qc = 1.f - pc;
        pse -= pc * logf(fmaxf(pc, FEPS)) + qc * logf(fmaxf(qc, FEPS));
    }
    out_idx[tok] = (float)idx;

    // sparse histogram over "soft" bits only
    unsigned int base = 0;
    int nsoft = 0;
    int softbit[14];
    float softp[14];
#pragma unroll
    for (int c = 0; c < 14; ++c) {
        if (p[c] == 1.f) {
            base |= (1u << (13 - c));
        } else if (p[c] != 0.f) {
            softbit[nsoft] = 13 - c;
            softp[nsoft] = p[c];
            ++nsoft;
        }
    }
    const int nsub = 1 << nsoft;
    for (int m = 0; m < nsub; ++m) {
        float pr = 1.f;
        unsigned int code = base;
        for (int j = 0; j < nsoft; ++j) {
            if (m & (1 << j)) { pr *= softp[j]; code |= (1u << softbit[j]); }
            else              { pr *= (1.f - softp[j]); }
        }
        atomicAdd(hist + code, pr);
    }

    sc[tid] = pse; __syncthreads();
    for (int s = 128; s > 0; s >>= 1) { if (tid < s) sc[tid] += sc[tid + s]; __syncthreads(); }
    const float ps_sum = sc[0]; __syncthreads();
    sc[tid] = commit; __syncthreads();
    for (int s = 128; s > 0; s >>= 1) { if (tid < s) sc[tid] += sc[tid + s]; __syncthreads(); }
    if (tid == 0) {
        pse_part[blockIdx.x] = ps_sum;
        commit_part[blockIdx.x] = sc[0];
    }
}

// ---------------------------------------------------------------------------
// Kernel: out[b][d][t] = sum_c sign_c * W_out[d][c] + b_out[d]  (float4)
// ---------------------------------------------------------------------------
__global__ __launch_bounds__(256) void k_proj_out(
    const float* __restrict__ idxf,
    const float* __restrict__ W_out,
    const float* __restrict__ b_out,
    float* __restrict__ out)
{
    const int base = blockIdx.x * 1024;          // element base
    const int b = base >> 20;
    const int d = (base >> 11) & (DIM - 1);
    const int t = (base & (TT - 1)) + threadIdx.x * 4;

    const float4 uf = *(const float4*)(idxf + b * TT + t);
    float w[14];
#pragma unroll
    for (int c = 0; c < 14; ++c) w[c] = W_out[d * 14 + c];
    const float bo = b_out[d];

    const float us[4] = {uf.x, uf.y, uf.z, uf.w};
    float4 o;
    float os[4];
#pragma unroll
    for (int j = 0; j < 4; ++j) {
        const unsigned int u = (unsigned int)us[j];
        float s = bo;
#pragma unroll
        for (int c = 0; c < 14; ++c)
            s += (u & (1u << (13 - c))) ? w[c] : -w[c];
        os[j] = s;
    }
    o.x = os[0]; o.y = os[1]; o.z = os[2]; o.w = os[3];
    *(float4*)(out + base + threadIdx.x * 4) = o;
}

// ---------------------------------------------------------------------------
// Finalize: codebook entropy + combine partials -> aux scalar
// ---------------------------------------------------------------------------
__global__ __launch_bounds__(256) void k_finalize(
    const float* __restrict__ hist,
    const float* __restrict__ pse_part,
    const float* __restrict__ commit_part,
    float* __restrict__ aux_out)
{
    __shared__ float sred[256];
    const int tid = threadIdx.x;

    float ce = 0.f;
    for (int j = tid; j < NB; j += 256) {
        const float a = hist[j] * (1.f / (float)NTOK);
        if (a > 0.f) ce -= a * logf(fmaxf(a, FEPS));
    }
    const float ps = pse_part[tid];
    const float cm = commit_part[tid];

    sred[tid] = ce; __syncthreads();
    for (int s = 128; s > 0; s >>= 1) { if (tid < s) sred[tid] += sred[tid + s]; __syncthreads(); }
    const float ce_sum = sred[0]; __syncthreads();

    sred[tid] = ps; __syncthreads();
    for (int s = 128; s > 0; s >>= 1) { if (tid < s) sred[tid] += sred[tid + s]; __syncthreads(); }
    const float ps_sum = sred[0]; __syncthreads();

    sred[tid] = cm; __syncthreads();
    for (int s = 128; s > 0; s >>= 1) { if (tid < s) sred[tid] += sred[tid + s]; __syncthreads(); }
    const float cm_sum = sred[0];

    if (tid == 0) {
        const float per_sample = ps_sum * (1.f / (float)NTOK);
        const float commit = cm_sum * (1.f / ((float)NTOK * (float)CDIM));
        aux_out[0] = (per_sample - ce_sum) * 0.1f + commit;
    }
}

// ---------------------------------------------------------------------------
// Fallback proj_in (R1-proven) in case ws is too small for partials
// ---------------------------------------------------------------------------
__global__ __launch_bounds__(256) void k_proj_in_fb(
    const float* __restrict__ x,
    const float* __restrict__ W_in,
    const float* __restrict__ b_in,
    float* __restrict__ out_idx,
    float* __restrict__ hist,
    float* __restrict__ pse_part,
    float* __restrict__ commit_part)
{
    __shared__ float Wl[DIM][16];
    __shared__ float red[8][32][14];

    const int tid = threadIdx.x;
    for (int i = tid; i < CDIM * DIM; i += 256) {
        const int c = i >> 9;
        const int d = i & (DIM - 1);
        Wl[d][c] = W_in[i];
    }
    __syncthreads();

    const int t_local = tid & 31;
    const int dg = tid >> 5;
    const int tg = blockIdx.x * 32 + t_local;
    const int b = tg >> 11;
    const int t = tg & (TT - 1);
    const float* xp = x + ((size_t)(b * DIM + dg * 64)) * TT + t;

    float acc[14];
#pragma unroll
    for (int c = 0; c < 14; ++c) acc[c] = 0.f;
#pragma unroll 8
    for (int i = 0; i < 64; ++i) {
        const float xv = xp[(size_t)i * TT];
        const float4* wr = (const float4*)(&Wl[dg * 64 + i][0]);
        const float4 w0 = wr[0];
        const float4 w1 = wr[1];
        const float4 w2 = wr[2];
        const float2 w3 = ((const float2*)wr)[6];
        acc[0]  = fmaf(xv, w0.x, acc[0]);
        acc[1]  = fmaf(xv, w0.y, acc[1]);
        acc[2]  = fmaf(xv, w0.z, acc[2]);
        acc[3]  = fmaf(xv, w0.w, acc[3]);
        acc[4]  = fmaf(xv, w1.x, acc[4]);
        acc[5]  = fmaf(xv, w1.y, acc[5]);
        acc[6]  = fmaf(xv, w1.z, acc[6]);
        acc[7]  = fmaf(xv, w1.w, acc[7]);
        acc[8]  = fmaf(xv, w2.x, acc[8]);
        acc[9]  = fmaf(xv, w2.y, acc[9]);
        acc[10] = fmaf(xv, w2.z, acc[10]);
        acc[11] = fmaf(xv, w2.w, acc[11]);
        acc[12] = fmaf(xv, w3.x, acc[12]);
        acc[13] = fmaf(xv, w3.y, acc[13]);
    }
#pragma unroll
    for (int c = 0; c < 14; ++c) red[dg][t_local][c] = acc[c];
    __syncthreads();

    float pse = 0.f, commit = 0.f;
    if (tid < 32) {
        float h[14];
#pragma unroll
        for (int c = 0; c < 14; ++c) {
            float s = b_in[c];
#pragma unroll
            for (int g = 0; g < 8; ++g) s += red[g][tid][c];
            h[c] = s;
        }
        unsigned int idx = 0;
        float p[14];
#pragma unroll
        for (int c = 0; c < 14; ++c) {
            const float hc = h[c];
            const bool pos = hc > 0.f;
            if (pos) idx |= (1u << (13 - c));
            const float sgn = pos ? 1.f : -1.f;
            const float dlt = hc - sgn;
            commit += dlt * dlt;
            const float pc = 1.f / (1.f + expf(-400.f * hc));
            p[c] = pc;
            const float qc = 1.f - pc;
            pse -= pc * logf(fmaxf(pc, FEPS)) + qc * logf(fmaxf(qc, FEPS));
        }
        out_idx[blockIdx.x * 32 + tid] = (float)idx;
        unsigned int base = 0;
        int nsoft = 0;
        int softbit[14];
        float softp[14];
#pragma unroll
        for (int c = 0; c < 14; ++c) {
            if (p[c] == 1.f) base |= (1u << (13 - c));
            else if (p[c] != 0.f) { softbit[nsoft] = 13 - c; softp[nsoft] = p[c]; ++nsoft; }
        }
        const int nsub = 1 << nsoft;
        for (int m = 0; m < nsub; ++m) {
            float pr = 1.f;
            unsigned int code = base;
            for (int j = 0; j < nsoft; ++j) {
                if (m & (1 << j)) { pr *= softp[j]; code |= (1u << softbit[j]); }
                else              { pr *= (1.f - softp[j]); }
            }
            atomicAdd(hist + code, pr);
        }
    }
    __syncthreads();
    float* sc = (float*)red;
    if (tid < 32) { sc[tid] = pse; sc[32 + tid] = commit; }
    __syncthreads();
    if (tid == 0) {
        float ps = 0.f, cm = 0.f;
        for (int i = 0; i < 32; ++i) { ps += sc[i]; cm += sc[32 + i]; }
        pse_part[blockIdx.x] = ps;
        commit_part[blockIdx.x] = cm;
    }
}

extern "C" void kernel_launch(void* const* d_in, const int* in_sizes, int n_in,
                              void* d_out, int out_size, void* d_ws, size_t ws_size,
                              hipStream_t stream)
{
    (void)in_sizes; (void)n_in; (void)out_size;

    const float* x     = (const float*)d_in[0];
    const float* W_in  = (const float*)d_in[1];
    const float* b_in  = (const float*)d_in[2];
    const float* W_out = (const float*)d_in[3];
    const float* b_out = (const float*)d_in[4];

    float* out     = (float*)d_out;
    float* out_idx = out + OUT_ELEMS;
    float* out_aux = out + OUT_ELEMS + NTOK;

    char* ws = (char*)d_ws;
    float* hist        = (float*)(ws + WS_HIST_OFF);
    float* pse_part    = (float*)(ws + WS_PSE_OFF);
    float* commit_part = (float*)(ws + WS_COM_OFF);
    float* pw          = (float*)(ws + WS_PW_OFF);

    hipMemsetAsync(d_ws, 0, WS_PW_OFF, stream);

    if (ws_size >= (size_t)WS_NEED) {
        k_partial<<<dim3(512), dim3(256), 0, stream>>>(x, W_in, pw);
        k_tail<<<dim3(NTOK / 256), dim3(256), 0, stream>>>(
            pw, b_in, out_idx, hist, pse_part, commit_part);
    } else {
        k_proj_in_fb<<<dim3(256), dim3(256), 0, stream>>>(
            x, W_in, b_in, out_idx, hist, pse_part, commit_part);
    }
    k_proj_out<<<dim3(OUT_ELEMS / 1024), dim3(256), 0, stream>>>(
        out_idx, W_out, b_out, out);
    k_finalize<<<dim3(1), dim3(256), 0, stream>>>(
        hist, pse_part, commit_part, out_aux);
}

// Round 3
// 70.606 us; speedup vs baseline: 1.6568x; 1.6568x over previous
//
#include <hip/hip_runtime.h>
#include <math.h>

#define BDIM 4
#define DIM 512
#define TT 2048
#define CDIM 14
#define NTOK (BDIM * TT)              // 8192 tokens
#define NB 16384                      // 2^14 codes
#define OUT_ELEMS (BDIM * DIM * TT)   // 4194304
#define FEPS 1e-20f

// ws layout
#define WS_HIST_OFF 0                 // 16384 f32 = 64 KB
#define WS_PSE_OFF 65536              // 256 f32
#define WS_COM_OFF 66560              // 256 f32
#define WS_PW_OFF  67584              // 4*14*8192 f32 = 1.75 MB
#define WS_NEED (67584 + 4 * 14 * 8192 * 4)

// ---------------------------------------------------------------------------
// Per-token tail math. NO runtime-indexed arrays (everything compile-time
// unrolled) so all state stays in VGPRs — the R2 version's softbit[]/softp[]
// went to scratch (VGPR_Count=40) and serialized on scratch loads (75us).
// ---------------------------------------------------------------------------
__device__ __forceinline__ void lfq_token_tail(
    const float* __restrict__ h,   // h[14], compile-time indexed by caller
    float* __restrict__ hist,
    unsigned int* idx_out, float* pse_out, float* commit_out)
{
    unsigned int idx = 0, softmask = 0, base = 0;
    float pse = 0.f, commit = 0.f;
    float pp[14], qq[14];
#pragma unroll
    for (int c = 0; c < 14; ++c) {
        const float hc = h[c];
        const unsigned int bit = 1u << (13 - c);
        const bool pos = hc > 0.f;
        if (pos) idx |= bit;
        const float sgn = pos ? 1.f : -1.f;
        const float dlt = hc - sgn;
        commit += dlt * dlt;
        const float pc = 1.f / (1.f + expf(-400.f * hc));  // sigmoid(400*h)
        const float qc = 1.f - pc;
        pse -= pc * logf(fmaxf(pc, FEPS)) + qc * logf(fmaxf(qc, FEPS));
        const bool hard1 = (pc == 1.f);
        const bool hard0 = (pc == 0.f);
        if (hard1) base |= bit;
        if (!hard1 && !hard0) softmask |= bit;
        pp[c] = (hard1 || hard0) ? 1.f : pc;
        qq[c] = (hard1 || hard0) ? 1.f : qc;
    }

    // enumerate all submasks s of softmask: s = (s-1) & softmask
    unsigned int s = softmask;
    while (true) {
        float f[14];
#pragma unroll
        for (int c = 0; c < 14; ++c)
            f[c] = (s & (1u << (13 - c))) ? pp[c] : qq[c];
        // multiply tree (4 levels)
        const float m0 = f[0] * f[1],  m1 = f[2] * f[3];
        const float m2 = f[4] * f[5],  m3 = f[6] * f[7];
        const float m4 = f[8] * f[9],  m5 = f[10] * f[11];
        const float m6 = f[12] * f[13];
        const float a0 = m0 * m1, a1 = m2 * m3, a2 = m4 * m5;
        const float pr = (a0 * a1) * (a2 * m6);
        atomicAdd(hist + (base | s), pr);
        if (s == 0) break;
        s = (s - 1) & softmask;
    }

    *idx_out = idx;
    *pse_out = pse;
    *commit_out = commit;
}

// ---------------------------------------------------------------------------
// Fast path kernel A: partial h. Grid 512 blocks x 256 thr.
// block = (token tile of 64) x (d-group of 128). Wave w covers 32 d's.
// ---------------------------------------------------------------------------
__global__ __launch_bounds__(256) void k_partial(
    const float* __restrict__ x,
    const float* __restrict__ W_in,
    float* __restrict__ pw)
{
    __shared__ float Wl[128][16];
    __shared__ float sred[4][64][15];

    const int tid = threadIdx.x;
    const int bid = blockIdx.x;
    const int tile = bid >> 2;
    const int dgrp = bid & 3;
    const int d0 = dgrp * 128;

    for (int i = tid; i < 128 * CDIM; i += 256) {
        const int c = i >> 7;
        const int r = i & 127;
        Wl[r][c] = W_in[c * DIM + d0 + r];
    }
    __syncthreads();

    const int w = tid >> 6;
    const int lane = tid & 63;
    const int tl = lane & 15;
    const int dr = lane >> 4;

    const int tok0 = tile * 64 + tl * 4;
    const int b = tok0 >> 11;
    const int t = tok0 & (TT - 1);
    const int wd0 = w * 32;

    float acc[4][14];
#pragma unroll
    for (int j = 0; j < 4; ++j)
#pragma unroll
        for (int c = 0; c < 14; ++c) acc[j][c] = 0.f;

#pragma unroll
    for (int i = 0; i < 8; ++i) {
        const int r = wd0 + i * 4 + dr;
        const float4 xv = *(const float4*)(x + ((size_t)(b * DIM + d0 + r) * TT + t));
        const float4* wr = (const float4*)(&Wl[r][0]);
        const float4 w0 = wr[0];
        const float4 w1 = wr[1];
        const float4 w2 = wr[2];
        const float2 w3 = ((const float2*)wr)[6];
        const float xs[4] = {xv.x, xv.y, xv.z, xv.w};
#pragma unroll
        for (int j = 0; j < 4; ++j) {
            const float v = xs[j];
            acc[j][0]  = fmaf(v, w0.x, acc[j][0]);
            acc[j][1]  = fmaf(v, w0.y, acc[j][1]);
            acc[j][2]  = fmaf(v, w0.z, acc[j][2]);
            acc[j][3]  = fmaf(v, w0.w, acc[j][3]);
            acc[j][4]  = fmaf(v, w1.x, acc[j][4]);
            acc[j][5]  = fmaf(v, w1.y, acc[j][5]);
            acc[j][6]  = fmaf(v, w1.z, acc[j][6]);
            acc[j][7]  = fmaf(v, w1.w, acc[j][7]);
            acc[j][8]  = fmaf(v, w2.x, acc[j][8]);
            acc[j][9]  = fmaf(v, w2.y, acc[j][9]);
            acc[j][10] = fmaf(v, w2.z, acc[j][10]);
            acc[j][11] = fmaf(v, w2.w, acc[j][11]);
            acc[j][12] = fmaf(v, w3.x, acc[j][12]);
            acc[j][13] = fmaf(v, w3.y, acc[j][13]);
        }
    }

#pragma unroll
    for (int j = 0; j < 4; ++j)
#pragma unroll
        for (int c = 0; c < 14; ++c) {
            float v = acc[j][c];
            v += __shfl_xor(v, 16);
            v += __shfl_xor(v, 32);
            acc[j][c] = v;
        }

    if (dr == 0) {
#pragma unroll
        for (int j = 0; j < 4; ++j)
#pragma unroll
            for (int c = 0; c < 14; ++c)
                sred[w][tl * 4 + j][c] = acc[j][c];
    }
    __syncthreads();

    for (int p = tid; p < 64 * CDIM; p += 256) {
        const int c = p >> 6;
        const int tk = p & 63;
        const float s = sred[0][tk][c] + sred[1][tk][c] + sred[2][tk][c] + sred[3][tk][c];
        pw[((dgrp * CDIM + c) << 13) + tile * 64 + tk] = s;
    }
}

// ---------------------------------------------------------------------------
// Fast path kernel B: per-token tail. 1 thread per token. 32 blocks x 256.
// ---------------------------------------------------------------------------
__global__ __launch_bounds__(256) void k_tail(
    const float* __restrict__ pw,
    const float* __restrict__ b_in,
    float* __restrict__ out_idx,
    float* __restrict__ hist,
    float* __restrict__ pse_part,
    float* __restrict__ commit_part)
{
    __shared__ float sc[256];
    const int tid = threadIdx.x;
    const int tok = blockIdx.x * 256 + tid;

    float h[14];
#pragma unroll
    for (int c = 0; c < 14; ++c) {
        float s = b_in[c];
#pragma unroll
        for (int g = 0; g < 4; ++g)
            s += pw[((g * CDIM + c) << 13) + tok];
        h[c] = s;
    }

    unsigned int idx;
    float pse, commit;
    lfq_token_tail(h, hist, &idx, &pse, &commit);
    out_idx[tok] = (float)idx;

    sc[tid] = pse; __syncthreads();
    for (int s = 128; s > 0; s >>= 1) { if (tid < s) sc[tid] += sc[tid + s]; __syncthreads(); }
    const float ps_sum = sc[0]; __syncthreads();
    sc[tid] = commit; __syncthreads();
    for (int s = 128; s > 0; s >>= 1) { if (tid < s) sc[tid] += sc[tid + s]; __syncthreads(); }
    if (tid == 0) {
        pse_part[blockIdx.x] = ps_sum;
        commit_part[blockIdx.x] = sc[0];
    }
}

// ---------------------------------------------------------------------------
// out[b][d][t] = sum_c sign_c * W_out[d][c] + b_out[d]  (float4 I/O)
// ---------------------------------------------------------------------------
__global__ __launch_bounds__(256) void k_proj_out(
    const float* __restrict__ idxf,
    const float* __restrict__ W_out,
    const float* __restrict__ b_out,
    float* __restrict__ out)
{
    const int base = blockIdx.x * 1024;
    const int b = base >> 20;
    const int d = (base >> 11) & (DIM - 1);
    const int t = (base & (TT - 1)) + threadIdx.x * 4;

    const float4 uf = *(const float4*)(idxf + b * TT + t);
    float w[14];
#pragma unroll
    for (int c = 0; c < 14; ++c) w[c] = W_out[d * 14 + c];
    const float bo = b_out[d];

    const float us[4] = {uf.x, uf.y, uf.z, uf.w};
    float os[4];
#pragma unroll
    for (int j = 0; j < 4; ++j) {
        const unsigned int u = (unsigned int)us[j];
        float s = bo;
#pragma unroll
        for (int c = 0; c < 14; ++c)
            s += (u & (1u << (13 - c))) ? w[c] : -w[c];
        os[j] = s;
    }
    float4 o; o.x = os[0]; o.y = os[1]; o.z = os[2]; o.w = os[3];
    *(float4*)(out + base + threadIdx.x * 4) = o;
}

// ---------------------------------------------------------------------------
// Finalize: codebook entropy + combine partials -> aux scalar. 1 block x 1024.
// ---------------------------------------------------------------------------
__global__ __launch_bounds__(1024) void k_finalize(
    const float* __restrict__ hist,
    const float* __restrict__ pse_part,
    const float* __restrict__ commit_part,
    float* __restrict__ aux_out)
{
    __shared__ float sred[1024];
    const int tid = threadIdx.x;

    float ce = 0.f;
#pragma unroll
    for (int rep = 0; rep < 4; ++rep) {
        const float4 hv = *(const float4*)(hist + (rep * 1024 + tid) * 4);
        const float hs[4] = {hv.x, hv.y, hv.z, hv.w};
#pragma unroll
        for (int j = 0; j < 4; ++j) {
            const float a = hs[j] * (1.f / (float)NTOK);
            if (a > 0.f) ce -= a * logf(fmaxf(a, FEPS));
        }
    }

    float ps = 0.f, cm = 0.f;
    if (tid < 32) { ps = pse_part[tid]; cm = commit_part[tid]; }

    sred[tid] = ce; __syncthreads();
    for (int s = 512; s > 0; s >>= 1) { if (tid < s) sred[tid] += sred[tid + s]; __syncthreads(); }
    const float ce_sum = sred[0]; __syncthreads();

    sred[tid] = ps; __syncthreads();
    for (int s = 512; s > 0; s >>= 1) { if (tid < s) sred[tid] += sred[tid + s]; __syncthreads(); }
    const float ps_sum = sred[0]; __syncthreads();

    sred[tid] = cm; __syncthreads();
    for (int s = 512; s > 0; s >>= 1) { if (tid < s) sred[tid] += sred[tid + s]; __syncthreads(); }
    const float cm_sum = sred[0];

    if (tid == 0) {
        const float per_sample = ps_sum * (1.f / (float)NTOK);
        const float commit = cm_sum * (1.f / ((float)NTOK * (float)CDIM));
        aux_out[0] = (per_sample - ce_sum) * 0.1f + commit;
    }
}

// ---------------------------------------------------------------------------
// Fallback proj_in (single-kernel) in case ws is too small for partials
// ---------------------------------------------------------------------------
__global__ __launch_bounds__(256) void k_proj_in_fb(
    const float* __restrict__ x,
    const float* __restrict__ W_in,
    const float* __restrict__ b_in,
    float* __restrict__ out_idx,
    float* __restrict__ hist,
    float* __restrict__ pse_part,
    float* __restrict__ commit_part)
{
    __shared__ float Wl[DIM][16];
    __shared__ float red[8][32][14];

    const int tid = threadIdx.x;
    for (int i = tid; i < CDIM * DIM; i += 256) {
        const int c = i >> 9;
        const int d = i & (DIM - 1);
        Wl[d][c] = W_in[i];
    }
    __syncthreads();

    const int t_local = tid & 31;
    const int dg = tid >> 5;
    const int tg = blockIdx.x * 32 + t_local;
    const int b = tg >> 11;
    const int t = tg & (TT - 1);
    const float* xp = x + ((size_t)(b * DIM + dg * 64)) * TT + t;

    float acc[14];
#pragma unroll
    for (int c = 0; c < 14; ++c) acc[c] = 0.f;
#pragma unroll 8
    for (int i = 0; i < 64; ++i) {
        const float xv = xp[(size_t)i * TT];
        const float4* wr = (const float4*)(&Wl[dg * 64 + i][0]);
        const float4 w0 = wr[0];
        const float4 w1 = wr[1];
        const float4 w2 = wr[2];
        const float2 w3 = ((const float2*)wr)[6];
        acc[0]  = fmaf(xv, w0.x, acc[0]);
        acc[1]  = fmaf(xv, w0.y, acc[1]);
        acc[2]  = fmaf(xv, w0.z, acc[2]);
        acc[3]  = fmaf(xv, w0.w, acc[3]);
        acc[4]  = fmaf(xv, w1.x, acc[4]);
        acc[5]  = fmaf(xv, w1.y, acc[5]);
        acc[6]  = fmaf(xv, w1.z, acc[6]);
        acc[7]  = fmaf(xv, w1.w, acc[7]);
        acc[8]  = fmaf(xv, w2.x, acc[8]);
        acc[9]  = fmaf(xv, w2.y, acc[9]);
        acc[10] = fmaf(xv, w2.z, acc[10]);
        acc[11] = fmaf(xv, w2.w, acc[11]);
        acc[12] = fmaf(xv, w3.x, acc[12]);
        acc[13] = fmaf(xv, w3.y, acc[13]);
    }
#pragma unroll
    for (int c = 0; c < 14; ++c) red[dg][t_local][c] = acc[c];
    __syncthreads();

    float pse = 0.f, commit = 0.f;
    if (tid < 32) {
        float h[14];
#pragma unroll
        for (int c = 0; c < 14; ++c) {
            float s = b_in[c];
#pragma unroll
            for (int g = 0; g < 8; ++g) s += red[g][tid][c];
            h[c] = s;
        }
        unsigned int idx;
        lfq_token_tail(h, hist, &idx, &pse, &commit);
        out_idx[blockIdx.x * 32 + tid] = (float)idx;
    }
    __syncthreads();
    float* sc = (float*)red;
    if (tid < 32) { sc[tid] = pse; sc[32 + tid] = commit; }
    __syncthreads();
    if (tid == 0) {
        float ps = 0.f, cm = 0.f;
        for (int i = 0; i < 32; ++i) { ps += sc[i]; cm += sc[32 + i]; }
        pse_part[blockIdx.x] = ps;
        commit_part[blockIdx.x] = cm;
    }
}

extern "C" void kernel_launch(void* const* d_in, const int* in_sizes, int n_in,
                              void* d_out, int out_size, void* d_ws, size_t ws_size,
                              hipStream_t stream)
{
    (void)in_sizes; (void)n_in; (void)out_size;

    const float* x     = (const float*)d_in[0];
    const float* W_in  = (const float*)d_in[1];
    const float* b_in  = (const float*)d_in[2];
    const float* W_out = (const float*)d_in[3];
    const float* b_out = (const float*)d_in[4];

    float* out     = (float*)d_out;
    float* out_idx = out + OUT_ELEMS;
    float* out_aux = out + OUT_ELEMS + NTOK;

    char* ws = (char*)d_ws;
    float* hist        = (float*)(ws + WS_HIST_OFF);
    float* pse_part    = (float*)(ws + WS_PSE_OFF);
    float* commit_part = (float*)(ws + WS_COM_OFF);
    float* pw          = (float*)(ws + WS_PW_OFF);

    hipMemsetAsync(d_ws, 0, WS_PW_OFF, stream);

    if (ws_size >= (size_t)WS_NEED) {
        k_partial<<<dim3(512), dim3(256), 0, stream>>>(x, W_in, pw);
        k_tail<<<dim3(NTOK / 256), dim3(256), 0, stream>>>(
            pw, b_in, out_idx, hist, pse_part, commit_part);
    } else {
        k_proj_in_fb<<<dim3(256), dim3(256), 0, stream>>>(
            x, W_in, b_in, out_idx, hist, pse_part, commit_part);
    }
    k_proj_out<<<dim3(OUT_ELEMS / 1024), dim3(256), 0, stream>>>(
        out_idx, W_out, b_out, out);
    k_finalize<<<dim3(1), dim3(1024), 0, stream>>>(
        hist, pse_part, commit_part, out_aux);
}

// Round 4
// 48.363 us; speedup vs baseline: 2.4188x; 1.4599x over previous
//
#include <hip/hip_runtime.h>
#include <math.h>

#define BDIM 4
#define DIM 512
#define TT 2048
#define CDIM 14
#define NTOK (BDIM * TT)              // 8192 tokens
#define NB 16384                      // 2^14 codes
#define OUT_ELEMS (BDIM * DIM * TT)   // 4194304
#define FEPS 1e-20f
#define PHARD 1e-6f                   // soft-bit cutoff (aux err <1e-5 vs thr 327)

// ws layout
#define WS_HIST_OFF 0                 // 16384 f32 = 64 KB
#define WS_PSE_OFF  65536             // 2048 f32 = 8 KB
#define WS_COM_OFF  73728             // 2048 f32 = 8 KB
#define WS_PW_OFF   81920             // 4*14*8192 f32 = 1.75 MB
#define WS_NEED (81920 + 4 * 14 * 8192 * 4)

// ---------------------------------------------------------------------------
// Kernel A: partial h. Grid 512 blocks x 256 thr.
// block = (token tile of 64) x (d-group of 128). Wave w covers 32 d's.
// ---------------------------------------------------------------------------
__global__ __launch_bounds__(256) void k_partial(
    const float* __restrict__ x,
    const float* __restrict__ W_in,
    float* __restrict__ pw)
{
    __shared__ float Wl[128][16];
    __shared__ float sred[4][64][15];

    const int tid = threadIdx.x;
    const int bid = blockIdx.x;
    const int tile = bid >> 2;
    const int dgrp = bid & 3;
    const int d0 = dgrp * 128;

    for (int i = tid; i < 128 * CDIM; i += 256) {
        const int c = i >> 7;
        const int r = i & 127;
        Wl[r][c] = W_in[c * DIM + d0 + r];
    }
    __syncthreads();

    const int w = tid >> 6;
    const int lane = tid & 63;
    const int tl = lane & 15;
    const int dr = lane >> 4;

    const int tok0 = tile * 64 + tl * 4;
    const int b = tok0 >> 11;
    const int t = tok0 & (TT - 1);
    const int wd0 = w * 32;

    float acc[4][14];
#pragma unroll
    for (int j = 0; j < 4; ++j)
#pragma unroll
        for (int c = 0; c < 14; ++c) acc[j][c] = 0.f;

#pragma unroll
    for (int i = 0; i < 8; ++i) {
        const int r = wd0 + i * 4 + dr;
        const float4 xv = *(const float4*)(x + ((size_t)(b * DIM + d0 + r) * TT + t));
        const float4* wr = (const float4*)(&Wl[r][0]);
        const float4 w0 = wr[0];
        const float4 w1 = wr[1];
        const float4 w2 = wr[2];
        const float2 w3 = ((const float2*)wr)[6];
        const float xs[4] = {xv.x, xv.y, xv.z, xv.w};
#pragma unroll
        for (int j = 0; j < 4; ++j) {
            const float v = xs[j];
            acc[j][0]  = fmaf(v, w0.x, acc[j][0]);
            acc[j][1]  = fmaf(v, w0.y, acc[j][1]);
            acc[j][2]  = fmaf(v, w0.z, acc[j][2]);
            acc[j][3]  = fmaf(v, w0.w, acc[j][3]);
            acc[j][4]  = fmaf(v, w1.x, acc[j][4]);
            acc[j][5]  = fmaf(v, w1.y, acc[j][5]);
            acc[j][6]  = fmaf(v, w1.z, acc[j][6]);
            acc[j][7]  = fmaf(v, w1.w, acc[j][7]);
            acc[j][8]  = fmaf(v, w2.x, acc[j][8]);
            acc[j][9]  = fmaf(v, w2.y, acc[j][9]);
            acc[j][10] = fmaf(v, w2.z, acc[j][10]);
            acc[j][11] = fmaf(v, w2.w, acc[j][11]);
            acc[j][12] = fmaf(v, w3.x, acc[j][12]);
            acc[j][13] = fmaf(v, w3.y, acc[j][13]);
        }
    }

#pragma unroll
    for (int j = 0; j < 4; ++j)
#pragma unroll
        for (int c = 0; c < 14; ++c) {
            float v = acc[j][c];
            v += __shfl_xor(v, 16);
            v += __shfl_xor(v, 32);
            acc[j][c] = v;
        }

    if (dr == 0) {
#pragma unroll
        for (int j = 0; j < 4; ++j)
#pragma unroll
            for (int c = 0; c < 14; ++c)
                sred[w][tl * 4 + j][c] = acc[j][c];
    }
    __syncthreads();

    for (int p = tid; p < 64 * CDIM; p += 256) {
        const int c = p >> 6;
        const int tk = p & 63;
        const float s = sred[0][tk][c] + sred[1][tk][c] + sred[2][tk][c] + sred[3][tk][c];
        pw[((dgrp * CDIM + c) << 13) + tile * 64 + tk] = s;
    }
}

// ---------------------------------------------------------------------------
// Kernel B: per-token tail, ONE WAVE PER TOKEN (2048 blocks x 256 = 4 waves).
// All lanes redundantly compute h/p/q (wave-uniform loads, pure VALU);
// subset enumeration parallelized over the 64 lanes. No runtime-indexed
// arrays anywhere; no address-taken locals (R3: scratch serialization).
// ---------------------------------------------------------------------------
__global__ __launch_bounds__(256) void k_tail_w(
    const float* __restrict__ pw,
    const float* __restrict__ b_in,
    float* __restrict__ out_idx,
    float* __restrict__ hist,
    float* __restrict__ pse_part,
    float* __restrict__ commit_part)
{
    __shared__ float sps[4], scm[4];
    const int tid = threadIdx.x;
    const int w = tid >> 6;
    const int lane = tid & 63;
    const int tok = blockIdx.x * 4 + w;

    float h[14];
#pragma unroll
    for (int c = 0; c < 14; ++c) {
        float s = b_in[c];
#pragma unroll
        for (int g = 0; g < 4; ++g)
            s += pw[((g * CDIM + c) << 13) + tok];
        h[c] = s;
    }

    unsigned int idx = 0, base = 0, softmask = 0;
    float pse = 0.f, commit = 0.f;
    float pp[14], qq[14];
#pragma unroll
    for (int c = 0; c < 14; ++c) {
        const float hc = h[c];
        const unsigned int bit = 1u << (13 - c);
        const bool pos = hc > 0.f;
        if (pos) idx |= bit;
        const float sgn = pos ? 1.f : -1.f;
        const float dlt = hc - sgn;
        commit += dlt * dlt;
        const float pc = 1.f / (1.f + expf(-400.f * hc));  // sigmoid(400h)
        const float qc = 1.f - pc;
        pse -= pc * logf(fmaxf(pc, FEPS)) + qc * logf(fmaxf(qc, FEPS));
        const bool hard1 = (qc <= PHARD);
        const bool hard0 = (pc <= PHARD);
        if (hard1) base |= bit;
        if (!hard1 && !hard0) softmask |= bit;
        pp[c] = pc;
        qq[c] = qc;
    }

    const unsigned int nsub = 1u << __popc(softmask);
    for (unsigned int m = lane; m < nsub; m += 64) {
        unsigned int rem = m, code = base;
        float pr = 1.f;
#pragma unroll
        for (int c = 0; c < 14; ++c) {
            const unsigned int bit = 1u << (13 - c);
            if (softmask & bit) {            // runtime cond, static indices
                const bool on = (rem & 1u) != 0u;
                pr *= on ? pp[c] : qq[c];
                if (on) code |= bit;
                rem >>= 1;
            }
        }
        atomicAdd(hist + code, pr);
    }

    if (lane == 0) {
        out_idx[tok] = (float)idx;
        sps[w] = pse;
        scm[w] = commit;
    }
    __syncthreads();
    if (tid == 0) {
        pse_part[blockIdx.x]    = (sps[0] + sps[1]) + (sps[2] + sps[3]);
        commit_part[blockIdx.x] = (scm[0] + scm[1]) + (scm[2] + scm[3]);
    }
}

// ---------------------------------------------------------------------------
// Kernel C: out[b][d][t] = sum_c sign_c*W_out[d][c] + b_out[d] (float4 I/O).
// Block 0 additionally computes the aux scalar (hist complete at launch by
// stream order; one extra ~2us on one block, saves a dispatch).
// ---------------------------------------------------------------------------
__global__ __launch_bounds__(256) void k_proj_out_fin(
    const float* __restrict__ idxf,
    const float* __restrict__ W_out,
    const float* __restrict__ b_out,
    float* __restrict__ out,
    const float* __restrict__ hist,
    const float* __restrict__ pse_part,
    const float* __restrict__ commit_part,
    float* __restrict__ aux_out)
{
    const int tid = threadIdx.x;
    const int base = blockIdx.x * 1024;
    const int b = base >> 20;
    const int d = (base >> 11) & (DIM - 1);
    const int t = (base & (TT - 1)) + tid * 4;

    const float4 uf = *(const float4*)(idxf + b * TT + t);
    float w[14];
#pragma unroll
    for (int c = 0; c < 14; ++c) w[c] = W_out[d * 14 + c];
    const float bo = b_out[d];

    const float us[4] = {uf.x, uf.y, uf.z, uf.w};
    float os[4];
#pragma unroll
    for (int j = 0; j < 4; ++j) {
        const unsigned int u = (unsigned int)us[j];
        float s = bo;
#pragma unroll
        for (int c = 0; c < 14; ++c)
            s += (u & (1u << (13 - c))) ? w[c] : -w[c];
        os[j] = s;
    }
    float4 o; o.x = os[0]; o.y = os[1]; o.z = os[2]; o.w = os[3];
    *(float4*)(out + base + tid * 4) = o;

    if (blockIdx.x != 0) return;

    // ---- finalize (block 0 only) ----
    __shared__ float sred[256];

    float ce = 0.f;
#pragma unroll
    for (int rep = 0; rep < 16; ++rep) {
        const float4 hv = *(const float4*)(hist + (rep * 256 + tid) * 4);
        const float hs[4] = {hv.x, hv.y, hv.z, hv.w};
#pragma unroll
        for (int j = 0; j < 4; ++j) {
            const float a = hs[j] * (1.f / (float)NTOK);
            if (a > 0.f) ce -= a * logf(fmaxf(a, FEPS));
        }
    }
    float ps = 0.f, cm = 0.f;
#pragma unroll
    for (int r = 0; r < 8; ++r) {
        ps += pse_part[r * 256 + tid];
        cm += commit_part[r * 256 + tid];
    }

    sred[tid] = ce; __syncthreads();
    for (int s = 128; s > 0; s >>= 1) { if (tid < s) sred[tid] += sred[tid + s]; __syncthreads(); }
    const float ce_sum = sred[0]; __syncthreads();

    sred[tid] = ps; __syncthreads();
    for (int s = 128; s > 0; s >>= 1) { if (tid < s) sred[tid] += sred[tid + s]; __syncthreads(); }
    const float ps_sum = sred[0]; __syncthreads();

    sred[tid] = cm; __syncthreads();
    for (int s = 128; s > 0; s >>= 1) { if (tid < s) sred[tid] += sred[tid + s]; __syncthreads(); }
    const float cm_sum = sred[0];

    if (tid == 0) {
        const float per_sample = ps_sum * (1.f / (float)NTOK);
        const float commit = cm_sum * (1.f / ((float)NTOK * (float)CDIM));
        aux_out[0] = (per_sample - ce_sum) * 0.1f + commit;
    }
}

// ---------------------------------------------------------------------------
// Fallback proj_in (single-kernel, serial subset walk) — only if ws too small.
// ---------------------------------------------------------------------------
__global__ __launch_bounds__(256) void k_proj_in_fb(
    const float* __restrict__ x,
    const float* __restrict__ W_in,
    const float* __restrict__ b_in,
    float* __restrict__ out_idx,
    float* __restrict__ hist,
    float* __restrict__ pse_part,
    float* __restrict__ commit_part)
{
    __shared__ float Wl[DIM][16];
    __shared__ float red[8][32][14];

    const int tid = threadIdx.x;
    for (int i = tid; i < CDIM * DIM; i += 256) {
        const int c = i >> 9;
        const int d = i & (DIM - 1);
        Wl[d][c] = W_in[i];
    }
    __syncthreads();

    const int t_local = tid & 31;
    const int dg = tid >> 5;
    const int tg = blockIdx.x * 32 + t_local;
    const int b = tg >> 11;
    const int t = tg & (TT - 1);
    const float* xp = x + ((size_t)(b * DIM + dg * 64)) * TT + t;

    float acc[14];
#pragma unroll
    for (int c = 0; c < 14; ++c) acc[c] = 0.f;
#pragma unroll 8
    for (int i = 0; i < 64; ++i) {
        const float xv = xp[(size_t)i * TT];
        const float4* wr = (const float4*)(&Wl[dg * 64 + i][0]);
        const float4 w0 = wr[0];
        const float4 w1 = wr[1];
        const float4 w2 = wr[2];
        const float2 w3 = ((const float2*)wr)[6];
        acc[0]  = fmaf(xv, w0.x, acc[0]);
        acc[1]  = fmaf(xv, w0.y, acc[1]);
        acc[2]  = fmaf(xv, w0.z, acc[2]);
        acc[3]  = fmaf(xv, w0.w, acc[3]);
        acc[4]  = fmaf(xv, w1.x, acc[4]);
        acc[5]  = fmaf(xv, w1.y, acc[5]);
        acc[6]  = fmaf(xv, w1.z, acc[6]);
        acc[7]  = fmaf(xv, w1.w, acc[7]);
        acc[8]  = fmaf(xv, w2.x, acc[8]);
        acc[9]  = fmaf(xv, w2.y, acc[9]);
        acc[10] = fmaf(xv, w2.z, acc[10]);
        acc[11] = fmaf(xv, w2.w, acc[11]);
        acc[12] = fmaf(xv, w3.x, acc[12]);
        acc[13] = fmaf(xv, w3.y, acc[13]);
    }
#pragma unroll
    for (int c = 0; c < 14; ++c) red[dg][t_local][c] = acc[c];
    __syncthreads();

    float pse = 0.f, commit = 0.f;
    if (tid < 32) {
        float h[14];
#pragma unroll
        for (int c = 0; c < 14; ++c) {
            float s = b_in[c];
#pragma unroll
            for (int g = 0; g < 8; ++g) s += red[g][tid][c];
            h[c] = s;
        }
        unsigned int idx = 0, base = 0, softmask = 0;
        float pp[14], qq[14];
#pragma unroll
        for (int c = 0; c < 14; ++c) {
            const float hc = h[c];
            const unsigned int bit = 1u << (13 - c);
            const bool pos = hc > 0.f;
            if (pos) idx |= bit;
            const float sgn = pos ? 1.f : -1.f;
            const float dlt = hc - sgn;
            commit += dlt * dlt;
            const float pc = 1.f / (1.f + expf(-400.f * hc));
            const float qc = 1.f - pc;
            pse -= pc * logf(fmaxf(pc, FEPS)) + qc * logf(fmaxf(qc, FEPS));
            const bool hard1 = (qc <= PHARD);
            const bool hard0 = (pc <= PHARD);
            if (hard1) base |= bit;
            if (!hard1 && !hard0) softmask |= bit;
            pp[c] = pc;
            qq[c] = qc;
        }
        out_idx[blockIdx.x * 32 + tid] = (float)idx;
        unsigned int s = softmask;
        while (true) {
            float pr = 1.f;
#pragma unroll
            for (int c = 0; c < 14; ++c) {
                const unsigned int bit = 1u << (13 - c);
                if (softmask & bit)
                    pr *= (s & bit) ? pp[c] : qq[c];
            }
            atomicAdd(hist + (base | s), pr);
            if (s == 0) break;
            s = (s - 1) & softmask;
        }
    }
    __syncthreads();
    float* sc = (float*)red;
    if (tid < 32) { sc[tid] = pse; sc[32 + tid] = commit; }
    __syncthreads();
    if (tid == 0) {
        float ps = 0.f, cm = 0.f;
        for (int i = 0; i < 32; ++i) { ps += sc[i]; cm += sc[32 + i]; }
        pse_part[blockIdx.x] = ps;
        commit_part[blockIdx.x] = cm;
    }
}

extern "C" void kernel_launch(void* const* d_in, const int* in_sizes, int n_in,
                              void* d_out, int out_size, void* d_ws, size_t ws_size,
                              hipStream_t stream)
{
    (void)in_sizes; (void)n_in; (void)out_size;

    const float* x     = (const float*)d_in[0];
    const float* W_in  = (const float*)d_in[1];
    const float* b_in  = (const float*)d_in[2];
    const float* W_out = (const float*)d_in[3];
    const float* b_out = (const float*)d_in[4];

    float* out     = (float*)d_out;
    float* out_idx = out + OUT_ELEMS;
    float* out_aux = out + OUT_ELEMS + NTOK;

    char* ws = (char*)d_ws;
    float* hist        = (float*)(ws + WS_HIST_OFF);
    float* pse_part    = (float*)(ws + WS_PSE_OFF);
    float* commit_part = (float*)(ws + WS_COM_OFF);
    float* pw          = (float*)(ws + WS_PW_OFF);

    hipMemsetAsync(d_ws, 0, WS_PW_OFF, stream);  // hist + partials

    if (ws_size >= (size_t)WS_NEED) {
        k_partial<<<dim3(512), dim3(256), 0, stream>>>(x, W_in, pw);
        k_tail_w<<<dim3(NTOK / 4), dim3(256), 0, stream>>>(
            pw, b_in, out_idx, hist, pse_part, commit_part);
    } else {
        k_proj_in_fb<<<dim3(256), dim3(256), 0, stream>>>(
            x, W_in, b_in, out_idx, hist, pse_part, commit_part);
    }
    k_proj_out_fin<<<dim3(OUT_ELEMS / 1024), dim3(256), 0, stream>>>(
        out_idx, W_out, b_out, out, hist, pse_part, commit_part, out_aux);
}

// Round 5
// 43.729 us; speedup vs baseline: 2.6752x; 1.1060x over previous
//
#include <hip/hip_runtime.h>
#include <math.h>

#define BDIM 4
#define DIM 512
#define TT 2048
#define CDIM 14
#define NTOK (BDIM * TT)              // 8192 tokens
#define NB 16384                      // 2^14 codes
#define OUT_ELEMS (BDIM * DIM * TT)   // 4194304
#define FEPS 1e-20f
#define PHARD 1e-6f                   // soft-bit cutoff (aux err <1e-5 vs thr 327)

// ws layout
#define WS_HIST_OFF 0                 // 16384 f32 = 64 KB
#define WS_PSE_OFF  65536             // 2048 f32 = 8 KB
#define WS_COM_OFF  73728             // 2048 f32 = 8 KB
#define WS_PW_OFF   81920             // 4*14*8192 f32 = 1.75 MB
#define WS_NEED (81920 + 4 * 14 * 8192 * 4)

// ---------------------------------------------------------------------------
// Kernel A: partial h. Grid 512 blocks x 256 thr.
// block = (token tile of 64) x (d-group of 128). Wave w covers 32 d's.
// Blocks 0..63 also zero the 16384-bin hist (replaces the runtime's
// fillBufferAligned node, which profiled at 41 us for an 80 KB fill — R4).
// Stream order makes this safe: k_tail_w's atomics start only after ALL
// k_partial blocks (incl. the zeroing) retire.
// ---------------------------------------------------------------------------
__global__ __launch_bounds__(256) void k_partial(
    const float* __restrict__ x,
    const float* __restrict__ W_in,
    float* __restrict__ pw,
    float* __restrict__ hist)
{
    __shared__ float Wl[128][16];
    __shared__ float sred[4][64][15];

    const int tid = threadIdx.x;
    const int bid = blockIdx.x;

    if (bid < 64) hist[bid * 256 + tid] = 0.f;   // zero hist in-pass

    const int tile = bid >> 2;
    const int dgrp = bid & 3;
    const int d0 = dgrp * 128;

    for (int i = tid; i < 128 * CDIM; i += 256) {
        const int c = i >> 7;
        const int r = i & 127;
        Wl[r][c] = W_in[c * DIM + d0 + r];
    }
    __syncthreads();

    const int w = tid >> 6;
    const int lane = tid & 63;
    const int tl = lane & 15;
    const int dr = lane >> 4;

    const int tok0 = tile * 64 + tl * 4;
    const int b = tok0 >> 11;
    const int t = tok0 & (TT - 1);
    const int wd0 = w * 32;

    float acc[4][14];
#pragma unroll
    for (int j = 0; j < 4; ++j)
#pragma unroll
        for (int c = 0; c < 14; ++c) acc[j][c] = 0.f;

#pragma unroll
    for (int i = 0; i < 8; ++i) {
        const int r = wd0 + i * 4 + dr;
        const float4 xv = *(const float4*)(x + ((size_t)(b * DIM + d0 + r) * TT + t));
        const float4* wr = (const float4*)(&Wl[r][0]);
        const float4 w0 = wr[0];
        const float4 w1 = wr[1];
        const float4 w2 = wr[2];
        const float2 w3 = ((const float2*)wr)[6];
        const float xs[4] = {xv.x, xv.y, xv.z, xv.w};
#pragma unroll
        for (int j = 0; j < 4; ++j) {
            const float v = xs[j];
            acc[j][0]  = fmaf(v, w0.x, acc[j][0]);
            acc[j][1]  = fmaf(v, w0.y, acc[j][1]);
            acc[j][2]  = fmaf(v, w0.z, acc[j][2]);
            acc[j][3]  = fmaf(v, w0.w, acc[j][3]);
            acc[j][4]  = fmaf(v, w1.x, acc[j][4]);
            acc[j][5]  = fmaf(v, w1.y, acc[j][5]);
            acc[j][6]  = fmaf(v, w1.z, acc[j][6]);
            acc[j][7]  = fmaf(v, w1.w, acc[j][7]);
            acc[j][8]  = fmaf(v, w2.x, acc[j][8]);
            acc[j][9]  = fmaf(v, w2.y, acc[j][9]);
            acc[j][10] = fmaf(v, w2.z, acc[j][10]);
            acc[j][11] = fmaf(v, w2.w, acc[j][11]);
            acc[j][12] = fmaf(v, w3.x, acc[j][12]);
            acc[j][13] = fmaf(v, w3.y, acc[j][13]);
        }
    }

#pragma unroll
    for (int j = 0; j < 4; ++j)
#pragma unroll
        for (int c = 0; c < 14; ++c) {
            float v = acc[j][c];
            v += __shfl_xor(v, 16);
            v += __shfl_xor(v, 32);
            acc[j][c] = v;
        }

    if (dr == 0) {
#pragma unroll
        for (int j = 0; j < 4; ++j)
#pragma unroll
            for (int c = 0; c < 14; ++c)
                sred[w][tl * 4 + j][c] = acc[j][c];
    }
    __syncthreads();

    for (int p = tid; p < 64 * CDIM; p += 256) {
        const int c = p >> 6;
        const int tk = p & 63;
        const float s = sred[0][tk][c] + sred[1][tk][c] + sred[2][tk][c] + sred[3][tk][c];
        pw[((dgrp * CDIM + c) << 13) + tile * 64 + tk] = s;
    }
}

// ---------------------------------------------------------------------------
// Kernel B: per-token tail, ONE WAVE PER TOKEN (2048 blocks x 256 = 4 waves).
// All lanes redundantly compute h/p/q (wave-uniform loads, pure VALU);
// subset enumeration parallelized over the 64 lanes. No runtime-indexed
// arrays anywhere; no address-taken locals (R3: scratch serialization).
// ---------------------------------------------------------------------------
__global__ __launch_bounds__(256) void k_tail_w(
    const float* __restrict__ pw,
    const float* __restrict__ b_in,
    float* __restrict__ out_idx,
    float* __restrict__ hist,
    float* __restrict__ pse_part,
    float* __restrict__ commit_part)
{
    __shared__ float sps[4], scm[4];
    const int tid = threadIdx.x;
    const int w = tid >> 6;
    const int lane = tid & 63;
    const int tok = blockIdx.x * 4 + w;

    float h[14];
#pragma unroll
    for (int c = 0; c < 14; ++c) {
        float s = b_in[c];
#pragma unroll
        for (int g = 0; g < 4; ++g)
            s += pw[((g * CDIM + c) << 13) + tok];
        h[c] = s;
    }

    unsigned int idx = 0, base = 0, softmask = 0;
    float pse = 0.f, commit = 0.f;
    float pp[14], qq[14];
#pragma unroll
    for (int c = 0; c < 14; ++c) {
        const float hc = h[c];
        const unsigned int bit = 1u << (13 - c);
        const bool pos = hc > 0.f;
        if (pos) idx |= bit;
        const float sgn = pos ? 1.f : -1.f;
        const float dlt = hc - sgn;
        commit += dlt * dlt;
        const float pc = 1.f / (1.f + expf(-400.f * hc));  // sigmoid(400h)
        const float qc = 1.f - pc;
        pse -= pc * logf(fmaxf(pc, FEPS)) + qc * logf(fmaxf(qc, FEPS));
        const bool hard1 = (qc <= PHARD);
        const bool hard0 = (pc <= PHARD);
        if (hard1) base |= bit;
        if (!hard1 && !hard0) softmask |= bit;
        pp[c] = pc;
        qq[c] = qc;
    }

    const unsigned int nsub = 1u << __popc(softmask);
    for (unsigned int m = lane; m < nsub; m += 64) {
        unsigned int rem = m, code = base;
        float pr = 1.f;
#pragma unroll
        for (int c = 0; c < 14; ++c) {
            const unsigned int bit = 1u << (13 - c);
            if (softmask & bit) {            // runtime cond, static indices
                const bool on = (rem & 1u) != 0u;
                pr *= on ? pp[c] : qq[c];
                if (on) code |= bit;
                rem >>= 1;
            }
        }
        atomicAdd(hist + code, pr);
    }

    if (lane == 0) {
        out_idx[tok] = (float)idx;
        sps[w] = pse;
        scm[w] = commit;
    }
    __syncthreads();
    if (tid == 0) {
        pse_part[blockIdx.x]    = (sps[0] + sps[1]) + (sps[2] + sps[3]);
        commit_part[blockIdx.x] = (scm[0] + scm[1]) + (scm[2] + scm[3]);
    }
}

// ---------------------------------------------------------------------------
// Kernel C: out[b][d][t] = sum_c sign_c*W_out[d][c] + b_out[d] (float4 I/O).
// Block 0 additionally computes the aux scalar (hist complete at launch by
// stream order; one extra ~2us on one block, saves a dispatch).
// ---------------------------------------------------------------------------
__global__ __launch_bounds__(256) void k_proj_out_fin(
    const float* __restrict__ idxf,
    const float* __restrict__ W_out,
    const float* __restrict__ b_out,
    float* __restrict__ out,
    const float* __restrict__ hist,
    const float* __restrict__ pse_part,
    const float* __restrict__ commit_part,
    float* __restrict__ aux_out)
{
    const int tid = threadIdx.x;
    const int base = blockIdx.x * 1024;
    const int b = base >> 20;
    const int d = (base >> 11) & (DIM - 1);
    const int t = (base & (TT - 1)) + tid * 4;

    const float4 uf = *(const float4*)(idxf + b * TT + t);
    float w[14];
#pragma unroll
    for (int c = 0; c < 14; ++c) w[c] = W_out[d * 14 + c];
    const float bo = b_out[d];

    const float us[4] = {uf.x, uf.y, uf.z, uf.w};
    float os[4];
#pragma unroll
    for (int j = 0; j < 4; ++j) {
        const unsigned int u = (unsigned int)us[j];
        float s = bo;
#pragma unroll
        for (int c = 0; c < 14; ++c)
            s += (u & (1u << (13 - c))) ? w[c] : -w[c];
        os[j] = s;
    }
    float4 o; o.x = os[0]; o.y = os[1]; o.z = os[2]; o.w = os[3];
    *(float4*)(out + base + tid * 4) = o;

    if (blockIdx.x != 0) return;

    // ---- finalize (block 0 only) ----
    __shared__ float sred[256];

    float ce = 0.f;
#pragma unroll
    for (int rep = 0; rep < 16; ++rep) {
        const float4 hv = *(const float4*)(hist + (rep * 256 + tid) * 4);
        const float hs[4] = {hv.x, hv.y, hv.z, hv.w};
#pragma unroll
        for (int j = 0; j < 4; ++j) {
            const float a = hs[j] * (1.f / (float)NTOK);
            if (a > 0.f) ce -= a * logf(fmaxf(a, FEPS));
        }
    }
    float ps = 0.f, cm = 0.f;
#pragma unroll
    for (int r = 0; r < 8; ++r) {
        ps += pse_part[r * 256 + tid];
        cm += commit_part[r * 256 + tid];
    }

    sred[tid] = ce; __syncthreads();
    for (int s = 128; s > 0; s >>= 1) { if (tid < s) sred[tid] += sred[tid + s]; __syncthreads(); }
    const float ce_sum = sred[0]; __syncthreads();

    sred[tid] = ps; __syncthreads();
    for (int s = 128; s > 0; s >>= 1) { if (tid < s) sred[tid] += sred[tid + s]; __syncthreads(); }
    const float ps_sum = sred[0]; __syncthreads();

    sred[tid] = cm; __syncthreads();
    for (int s = 128; s > 0; s >>= 1) { if (tid < s) sred[tid] += sred[tid + s]; __syncthreads(); }
    const float cm_sum = sred[0];

    if (tid == 0) {
        const float per_sample = ps_sum * (1.f / (float)NTOK);
        const float commit = cm_sum * (1.f / ((float)NTOK * (float)CDIM));
        aux_out[0] = (per_sample - ce_sum) * 0.1f + commit;
    }
}

// ---------------------------------------------------------------------------
// Fallback proj_in (single-kernel, serial subset walk) — only if ws too small.
// ---------------------------------------------------------------------------
__global__ __launch_bounds__(256) void k_proj_in_fb(
    const float* __restrict__ x,
    const float* __restrict__ W_in,
    const float* __restrict__ b_in,
    float* __restrict__ out_idx,
    float* __restrict__ hist,
    float* __restrict__ pse_part,
    float* __restrict__ commit_part)
{
    __shared__ float Wl[DIM][16];
    __shared__ float red[8][32][14];

    const int tid = threadIdx.x;
    for (int i = tid; i < CDIM * DIM; i += 256) {
        const int c = i >> 9;
        const int d = i & (DIM - 1);
        Wl[d][c] = W_in[i];
    }
    __syncthreads();

    const int t_local = tid & 31;
    const int dg = tid >> 5;
    const int tg = blockIdx.x * 32 + t_local;
    const int b = tg >> 11;
    const int t = tg & (TT - 1);
    const float* xp = x + ((size_t)(b * DIM + dg * 64)) * TT + t;

    float acc[14];
#pragma unroll
    for (int c = 0; c < 14; ++c) acc[c] = 0.f;
#pragma unroll 8
    for (int i = 0; i < 64; ++i) {
        const float xv = xp[(size_t)i * TT];
        const float4* wr = (const float4*)(&Wl[dg * 64 + i][0]);
        const float4 w0 = wr[0];
        const float4 w1 = wr[1];
        const float4 w2 = wr[2];
        const float2 w3 = ((const float2*)wr)[6];
        acc[0]  = fmaf(xv, w0.x, acc[0]);
        acc[1]  = fmaf(xv, w0.y, acc[1]);
        acc[2]  = fmaf(xv, w0.z, acc[2]);
        acc[3]  = fmaf(xv, w0.w, acc[3]);
        acc[4]  = fmaf(xv, w1.x, acc[4]);
        acc[5]  = fmaf(xv, w1.y, acc[5]);
        acc[6]  = fmaf(xv, w1.z, acc[6]);
        acc[7]  = fmaf(xv, w1.w, acc[7]);
        acc[8]  = fmaf(xv, w2.x, acc[8]);
        acc[9]  = fmaf(xv, w2.y, acc[9]);
        acc[10] = fmaf(xv, w2.z, acc[10]);
        acc[11] = fmaf(xv, w2.w, acc[11]);
        acc[12] = fmaf(xv, w3.x, acc[12]);
        acc[13] = fmaf(xv, w3.y, acc[13]);
    }
#pragma unroll
    for (int c = 0; c < 14; ++c) red[dg][t_local][c] = acc[c];
    __syncthreads();

    float pse = 0.f, commit = 0.f;
    if (tid < 32) {
        float h[14];
#pragma unroll
        for (int c = 0; c < 14; ++c) {
            float s = b_in[c];
#pragma unroll
            for (int g = 0; g < 8; ++g) s += red[g][tid][c];
            h[c] = s;
        }
        unsigned int idx = 0, base = 0, softmask = 0;
        float pp[14], qq[14];
#pragma unroll
        for (int c = 0; c < 14; ++c) {
            const float hc = h[c];
            const unsigned int bit = 1u << (13 - c);
            const bool pos = hc > 0.f;
            if (pos) idx |= bit;
            const float sgn = pos ? 1.f : -1.f;
            const float dlt = hc - sgn;
            commit += dlt * dlt;
            const float pc = 1.f / (1.f + expf(-400.f * hc));
            const float qc = 1.f - pc;
            pse -= pc * logf(fmaxf(pc, FEPS)) + qc * logf(fmaxf(qc, FEPS));
            const bool hard1 = (qc <= PHARD);
            const bool hard0 = (pc <= PHARD);
            if (hard1) base |= bit;
            if (!hard1 && !hard0) softmask |= bit;
            pp[c] = pc;
            qq[c] = qc;
        }
        out_idx[blockIdx.x * 32 + tid] = (float)idx;
        unsigned int s = softmask;
        while (true) {
            float pr = 1.f;
#pragma unroll
            for (int c = 0; c < 14; ++c) {
                const unsigned int bit = 1u << (13 - c);
                if (softmask & bit)
                    pr *= (s & bit) ? pp[c] : qq[c];
            }
            atomicAdd(hist + (base | s), pr);
            if (s == 0) break;
            s = (s - 1) & softmask;
        }
    }
    __syncthreads();
    float* sc = (float*)red;
    if (tid < 32) { sc[tid] = pse; sc[32 + tid] = commit; }
    __syncthreads();
    if (tid == 0) {
        float ps = 0.f, cm = 0.f;
        for (int i = 0; i < 32; ++i) { ps += sc[i]; cm += sc[32 + i]; }
        pse_part[blockIdx.x] = ps;
        commit_part[blockIdx.x] = cm;
    }
}

extern "C" void kernel_launch(void* const* d_in, const int* in_sizes, int n_in,
                              void* d_out, int out_size, void* d_ws, size_t ws_size,
                              hipStream_t stream)
{
    (void)in_sizes; (void)n_in; (void)out_size;

    const float* x     = (const float*)d_in[0];
    const float* W_in  = (const float*)d_in[1];
    const float* b_in  = (const float*)d_in[2];
    const float* W_out = (const float*)d_in[3];
    const float* b_out = (const float*)d_in[4];

    float* out     = (float*)d_out;
    float* out_idx = out + OUT_ELEMS;
    float* out_aux = out + OUT_ELEMS + NTOK;

    char* ws = (char*)d_ws;
    float* hist        = (float*)(ws + WS_HIST_OFF);
    float* pse_part    = (float*)(ws + WS_PSE_OFF);
    float* commit_part = (float*)(ws + WS_COM_OFF);
    float* pw          = (float*)(ws + WS_PW_OFF);

    if (ws_size >= (size_t)WS_NEED) {
        // no memset: hist is zeroed inside k_partial (R4: the runtime's
        // 80 KB fill node profiled at 41 us — dominated the whole graph)
        k_partial<<<dim3(512), dim3(256), 0, stream>>>(x, W_in, pw, hist);
        k_tail_w<<<dim3(NTOK / 4), dim3(256), 0, stream>>>(
            pw, b_in, out_idx, hist, pse_part, commit_part);
    } else {
        hipMemsetAsync(d_ws, 0, WS_PW_OFF, stream);
        k_proj_in_fb<<<dim3(256), dim3(256), 0, stream>>>(
            x, W_in, b_in, out_idx, hist, pse_part, commit_part);
    }
    k_proj_out_fin<<<dim3(OUT_ELEMS / 1024), dim3(256), 0, stream>>>(
        out_idx, W_out, b_out, out, hist, pse_part, commit_part, out_aux);
}